// Round 6
// baseline (218.524 us; speedup 1.0000x reference)
//
#include <hip/hip_runtime.h>
#include <hip/hip_cooperative_groups.h>
#include <math.h>

namespace cg = cooperative_groups;

namespace {

constexpr int BB  = 4;    // batch
constexpr int SS  = 512;  // detector bins == image size
constexpr int AA  = 180;  // angles
constexpr int PAD = 112;  // LDS row zero-pad each side: p in [6.1, 728.9]
constexpr int ROWBUF = SS + 2 * PAD;  // 736 floats

struct RampShared {                    // 12.4 KB
  float xs[2][2][256];                 // [col][m-parity][m>>1]
  float G[2][528];                     // per-parity scaled taps
};
struct BpShared {                      // 18.4 KB
  float  rows[2][3][ROWBUF];
  float2 trig[90];
};
constexpr size_t SMEM_BYTES =
    sizeof(BpShared) > sizeof(RampShared) ? sizeof(BpShared) : sizeof(RampShared);

// 8B LDS load with 4B alignment -> guaranteed ds_read2_b32 (ONE DS instr per
// sample instead of two ds_read_b32 — R4's 54us matched the 2-instr floor).
__device__ __forceinline__ float2 lds_load_pair(const float* p) {
  float2 v;
  __builtin_memcpy(&v, p, sizeof(float2));
  return v;
}

// ---- phase 0: zero `out` (512 blocks x 256 thr x 2 float4 = 1M floats) ----
__device__ __forceinline__ void phase0_zero(int bid, int t, float* out) {
  float4 z = make_float4(0.f, 0.f, 0.f, 0.f);
  ((float4*)out)[bid * 512 + t]       = z;
  ((float4*)out)[bid * 512 + 256 + t] = z;
}

// ---- phase 1: ramp filter (R4 kernel, verified absmax 9.77e-4) -------------
// blocks 0..359, 2 angle-columns each; y[n] = s*0.5*x[n] + sum_j taps*x[m].
__device__ __forceinline__ void phase1_ramp(int bid, int t, const float* x,
                                            float* xf, RampShared& S) {
  const int b  = bid / 90;
  const int a0 = (bid - b * 90) * 2;

  const float s  = (float)(M_PI / 360.0);
  const float cc = (float)(-2.0 / (M_PI * M_PI)) * s;
  for (int i = t; i < 528; i += 256) {
    { int kk = i;     float d = (float)(2 * kk - 511); S.G[0][i] = (kk < 512) ? cc / (d * d) : 0.0f; }
    { int kk = i + 1; float d = (float)(2 * kk - 511); S.G[1][i] = (kk < 512) ? cc / (d * d) : 0.0f; }
  }

  const float* xb = x + (size_t)b * (SS * AA) + a0;
  {
    int m = t;
    float2 v = *(const float2*)(xb + (size_t)m * AA);
    S.xs[0][m & 1][m >> 1] = v.x;  S.xs[1][m & 1][m >> 1] = v.y;
    m = t + 256;
    float2 v2 = *(const float2*)(xb + (size_t)m * AA);
    S.xs[0][m & 1][m >> 1] = v2.x; S.xs[1][m & 1][m >> 1] = v2.y;
  }
  __syncthreads();

  const int col = t >> 7;
  const int p   = (t >> 6) & 1;
  const int idx = t & 63;
  const float* Gp = S.G[p];
  const float* xv = S.xs[col][1 - p];

  float acc[4] = {0.f, 0.f, 0.f, 0.f};
  float W[8];  // W[s] = Gp[A0 + s], A0 = 4*idx + 252 - 4q; slot(r,d) = 3+r-d
  {
    const int A0 = 4 * idx + 252;
    float4 w0 = *(const float4*)(Gp + A0);
    float4 w1 = *(const float4*)(Gp + A0 + 4);
    W[0] = w0.x; W[1] = w0.y; W[2] = w0.z; W[3] = w0.w;
    W[4] = w1.x; W[5] = w1.y; W[6] = w1.z; W[7] = w1.w;
  }

#pragma unroll
  for (int q = 0; q < 64; ++q) {
    const float4 xq = *(const float4*)(xv + 4 * q);  // broadcast
    float4 nw;
    if (q != 63) nw = *(const float4*)(Gp + (4 * idx + 252 - 4 * (q + 1)));
#pragma unroll
    for (int r = 0; r < 4; ++r) {
      acc[r] = fmaf(W[3 + r], xq.x, acc[r]);
      acc[r] = fmaf(W[2 + r], xq.y, acc[r]);
      acc[r] = fmaf(W[1 + r], xq.z, acc[r]);
      acc[r] = fmaf(W[0 + r], xq.w, acc[r]);
    }
    if (q != 63) {
      W[7] = W[3]; W[6] = W[2]; W[5] = W[1]; W[4] = W[0];
      W[0] = nw.x; W[1] = nw.y; W[2] = nw.z; W[3] = nw.w;
    }
  }

  const float selfc = 0.5f * s;
  const float* xsp = S.xs[col][p];
  float* orow = xf + ((size_t)(b * AA + a0 + col)) * SS;
#pragma unroll
  for (int r = 0; r < 4; ++r)
    orow[p + 8 * idx + 2 * r] = fmaf(selfc, xsp[4 * idx + r], acc[r]);
}

// ---- phase 2: backprojection, 512 jobs of 128x32 px x 90 angles ------------
// bid bits: tx(2) ty(4) z(3); z = b*2 + angle-half. 16 px/thread (2 x-cols x
// 8 y-rows). 30 groups of 3 angles, double-buffered global_load_lds DMA.
// Per sample: 7 VALU + 1 ds_read2_b32. 2 writers/px -> unsafeAtomicAdd.
__device__ __forceinline__ void phase2_bp(int bid, int t, const float* xf,
                                          float* out, BpShared& S) {
  const int tx   = bid & 3;           // 0..3  x-tile (128 px)
  const int ty   = (bid >> 2) & 15;   // 0..15 y-tile (32 px)
  const int z    = bid >> 6;          // 0..7
  const int b    = z >> 1;
  const int a0   = (z & 1) * 90;
  const int w    = t >> 6;
  const int lane = t & 63;

  // zero pad regions once
  for (int i = t; i < 2 * 3 * 2 * PAD; i += 256) {
    int rr = i / (2 * PAD);
    int o  = i - rr * (2 * PAD);
    int off = (o < PAD) ? o : (o + SS);
    S.rows[rr / 3][rr % 3][off] = 0.0f;
  }
  if (t < 90) {
    float th = (float)(a0 + t) * (float)(M_PI / 180.0);
    float sn, cn;
    sincosf(th, &sn, &cn);
    S.trig[t] = make_float2(cn * 255.5f, sn * 255.5f);
  }

  const float* xf_src = xf + ((size_t)b * AA + a0) * SS;

  auto stage = [&](int g, int buf) {
    const float* base = xf_src + (size_t)(g * 3) * SS;
    {
      const int sg = w;
      const float* gp = base + (sg >> 1) * SS + (sg & 1) * 256 + lane * 4;
      void* lp = (void*)&S.rows[buf][sg >> 1][PAD + (sg & 1) * 256];
      __builtin_amdgcn_global_load_lds(
          (const __attribute__((address_space(1))) void*)gp,
          (__attribute__((address_space(3))) void*)lp, 16, 0, 0);
    }
    if (w < 2) {
      const int sg = 4 + w;
      const float* gp = base + (sg >> 1) * SS + (sg & 1) * 256 + lane * 4;
      void* lp = (void*)&S.rows[buf][sg >> 1][PAD + (sg & 1) * 256];
      __builtin_amdgcn_global_load_lds(
          (const __attribute__((address_space(1))) void*)gp,
          (__attribute__((address_space(3))) void*)lp, 16, 0, 0);
    }
  };

  const int gx0 = tx * 128 + lane;    // second column: gx0 + 64
  // EXACT replication of jnp.linspace(-1,1,512) + f32 mask math (no FMA!)
  const float step = 2.0f / 511.0f;
  const float xg0 = __fadd_rn(-1.0f, __fmul_rn((float)gx0, step));
  const float xg1 = __fadd_rn(-1.0f, __fmul_rn((float)(gx0 + 64), step));
  float dy[8];  // dy = -yg (negation exact; dy*dy == yg*yg bitwise)
#pragma unroll
  for (int kk = 0; kk < 8; ++kk) {
    int gy = ty * 32 + w + 4 * kk;
    dy[kk] = -__fadd_rn(-1.0f, __fmul_rn((float)gy, step));
  }

  const float Kp = 255.5f + (float)PAD;
  float acc0[8], acc1[8];
#pragma unroll
  for (int kk = 0; kk < 8; ++kk) { acc0[kk] = 0.f; acc1[kk] = 0.f; }

  stage(0, 0);
  __syncthreads();

  int buf = 0;
  for (int g = 0; g < 30; ++g) {
    if (g + 1 < 30) stage(g + 1, buf ^ 1);
#pragma unroll
    for (int aa = 0; aa < 3; ++aa) {
      const float2 cs = S.trig[g * 3 + aa];
      const float base0 = fmaf(xg0, cs.x, Kp);
      const float base1 = fmaf(xg1, cs.x, Kp);
      const float* R = S.rows[buf][aa];
#pragma unroll
      for (int kk = 0; kk < 8; ++kk) {
        float p0 = fmaf(dy[kk], cs.y, base0);  // > 0 always
        float p1 = fmaf(dy[kk], cs.y, base1);
        int   i0 = (int)p0;
        int   i1 = (int)p1;
#if __has_builtin(__builtin_amdgcn_fractf)
        float w0 = __builtin_amdgcn_fractf(p0);
        float w1 = __builtin_amdgcn_fractf(p1);
#else
        float w0 = p0 - floorf(p0);
        float w1 = p1 - floorf(p1);
#endif
        float2 ab0 = lds_load_pair(R + i0);    // ds_read2_b32
        float2 ab1 = lds_load_pair(R + i1);
        acc0[kk] = fmaf(w0, ab0.y - ab0.x, acc0[kk] + ab0.x);
        acc1[kk] = fmaf(w1, ab1.y - ab1.x, acc1[kk] + ab1.x);
      }
    }
    __syncthreads();
    buf ^= 1;
  }

  // epilogue: circle mask folded into predicated atomic (out zeroed phase 0)
  const float xx0 = __fmul_rn(xg0, xg0);
  const float xx1 = __fmul_rn(xg1, xg1);
#pragma unroll
  for (int kk = 0; kk < 8; ++kk) {
    int gy = ty * 32 + w + 4 * kk;
    float yy = __fmul_rn(dy[kk], dy[kk]);
    float s0 = __fadd_rn(xx0, yy);
    float s1 = __fadd_rn(xx1, yy);
    float* orow = out + ((size_t)b * SS + gy) * SS;
    if (s0 <= 1.0f) unsafeAtomicAdd(&orow[gx0], acc0[kk]);
    if (s1 <= 1.0f) unsafeAtomicAdd(&orow[gx0 + 64], acc1[kk]);
  }
}

// ---------------------------------------------------------------------------
// Cooperative fused kernel (512 blocks = 2/CU: 2x margin under any coop
// co-residency limit — R5's 1024 sat at the boundary and the launch FAILED).
// ---------------------------------------------------------------------------
__global__ __launch_bounds__(256, 4) void fused_coop(
    const float* __restrict__ x, float* __restrict__ xf, float* __restrict__ out) {
  __shared__ __align__(16) char smem[SMEM_BYTES];
  const int t   = threadIdx.x;
  const int bid = blockIdx.x;
  phase0_zero(bid, t, out);
  if (bid < 360) phase1_ramp(bid, t, x, xf, *(RampShared*)smem);
  cg::this_grid().sync();
  phase2_bp(bid, t, xf, out, *(BpShared*)smem);
}

// Fallback 2-node pipeline (same phase functions, no grid sync needed):
__global__ __launch_bounds__(256, 4) void k_pre(
    const float* __restrict__ x, float* __restrict__ xf, float* __restrict__ out) {
  __shared__ __align__(16) char smem[sizeof(RampShared)];
  const int t = threadIdx.x, bid = blockIdx.x;
  phase0_zero(bid, t, out);
  if (bid < 360) phase1_ramp(bid, t, x, xf, *(RampShared*)smem);
}
__global__ __launch_bounds__(256, 4) void k_bp(
    const float* __restrict__ xf, float* __restrict__ out) {
  __shared__ __align__(16) char smem[sizeof(BpShared)];
  phase2_bp(blockIdx.x, threadIdx.x, xf, out, *(BpShared*)smem);
}

}  // namespace

extern "C" void kernel_launch(void* const* d_in, const int* in_sizes, int n_in,
                              void* d_out, int out_size, void* d_ws, size_t ws_size,
                              hipStream_t stream) {
  const float* x   = (const float*)d_in[0];
  float*       out = (float*)d_out;
  float*       xf  = (float*)d_ws;  // [B][A][S] = 1.44 MB

  void* args[3] = {(void*)&x, (void*)&xf, (void*)&out};
  hipError_t err = hipLaunchCooperativeKernel((const void*)fused_coop,
                                              dim3(512), dim3(256), args, 0, stream);
  if (err != hipSuccess) {
    // deterministic fallback: same phases, 2 graph nodes
    k_pre<<<dim3(512), 256, 0, stream>>>(x, xf, out);
    k_bp<<<dim3(512), 256, 0, stream>>>(xf, out);
  }
}

// Round 7
// 99.858 us; speedup vs baseline: 2.1883x; 2.1883x over previous
//
#include <hip/hip_runtime.h>
#include <math.h>

namespace {

constexpr int BB  = 4;    // batch
constexpr int SS  = 512;  // detector bins == image size
constexpr int AA  = 180;  // angles
constexpr int PAD = 112;  // row zero-pad each side: p in [6.1, 728.9]
constexpr int RB  = SS + 2 * PAD;  // 736 entries

typedef float v2f __attribute__((ext_vector_type(2)));

// ---------------------------------------------------------------------------
// Kernel A: zero `out` + ramp filter (R4-verified math, absmax 9.77e-4).
// Grid (90, 4): block = 2 angle-columns, full K, direct stores; plus each
// block zeros a slice of out (replaces the memset node).
// ---------------------------------------------------------------------------
__global__ __launch_bounds__(256) void ramp_zero_kernel(
    const float* __restrict__ x, float* __restrict__ xf, float* __restrict__ out) {
  const int t = threadIdx.x;
  {  // zero out: 262144 float4 over 360 blocks
    const int bid = blockIdx.y * 90 + blockIdx.x;
    float4 z = make_float4(0.f, 0.f, 0.f, 0.f);
    for (int i = bid * 256 + t; i < (BB * SS * SS) / 4; i += 360 * 256)
      ((float4*)out)[i] = z;
  }

  __shared__ __align__(16) float xs[2][2][256];  // [col][m-parity][m>>1]
  __shared__ __align__(16) float G[2][528];      // per-parity scaled taps
  const int a0 = blockIdx.x * 2;
  const int b  = blockIdx.y;

  const float s  = (float)(M_PI / 360.0);
  const float cc = (float)(-2.0 / (M_PI * M_PI)) * s;
  for (int i = t; i < 528; i += 256) {
    { int kk = i;     float d = (float)(2 * kk - 511); G[0][i] = (kk < 512) ? cc / (d * d) : 0.0f; }
    { int kk = i + 1; float d = (float)(2 * kk - 511); G[1][i] = (kk < 512) ? cc / (d * d) : 0.0f; }
  }

  const float* xb = x + (size_t)b * (SS * AA) + a0;
  {
    int m = t;
    float2 v = *(const float2*)(xb + (size_t)m * AA);
    xs[0][m & 1][m >> 1] = v.x;  xs[1][m & 1][m >> 1] = v.y;
    m = t + 256;
    float2 v2 = *(const float2*)(xb + (size_t)m * AA);
    xs[0][m & 1][m >> 1] = v2.x; xs[1][m & 1][m >> 1] = v2.y;
  }
  __syncthreads();

  const int col = t >> 7;
  const int p   = (t >> 6) & 1;
  const int idx = t & 63;
  const float* Gp = G[p];
  const float* xv = xs[col][1 - p];

  float acc[4] = {0.f, 0.f, 0.f, 0.f};
  float W[8];  // W[s] = Gp[A0 + s], A0 = 4*idx + 252 - 4q; slot(r,d) = 3+r-d
  {
    const int A0 = 4 * idx + 252;
    float4 w0 = *(const float4*)(Gp + A0);
    float4 w1 = *(const float4*)(Gp + A0 + 4);
    W[0] = w0.x; W[1] = w0.y; W[2] = w0.z; W[3] = w0.w;
    W[4] = w1.x; W[5] = w1.y; W[6] = w1.z; W[7] = w1.w;
  }

#pragma unroll
  for (int q = 0; q < 64; ++q) {
    const float4 xq = *(const float4*)(xv + 4 * q);  // broadcast
    float4 nw;
    if (q != 63) nw = *(const float4*)(Gp + (4 * idx + 252 - 4 * (q + 1)));
#pragma unroll
    for (int r = 0; r < 4; ++r) {
      acc[r] = fmaf(W[3 + r], xq.x, acc[r]);
      acc[r] = fmaf(W[2 + r], xq.y, acc[r]);
      acc[r] = fmaf(W[1 + r], xq.z, acc[r]);
      acc[r] = fmaf(W[0 + r], xq.w, acc[r]);
    }
    if (q != 63) {
      W[7] = W[3]; W[6] = W[2]; W[5] = W[1]; W[4] = W[0];
      W[0] = nw.x; W[1] = nw.y; W[2] = nw.z; W[3] = nw.w;
    }
  }

  const float selfc = 0.5f * s;
  const float* xsp = xs[col][p];
  float* orow = xf + ((size_t)(b * AA + a0 + col)) * SS;
#pragma unroll
  for (int r = 0; r < 4; ++r)
    orow[p + 8 * idx + 2 * r] = fmaf(selfc, xsp[4 * idx + r], acc[r]);
}

// ---------------------------------------------------------------------------
// Kernel B: backprojection with point-reflection pairing.
// Pixel (gx,gy), gx in [0,256), pairs with (511-gx, 511-gy): p' = 735 - p
// exactly, so storing each row as P[j] = (row[j], row[735-j]) makes the
// mirrored sample a lerp over (P[I].y, P[I+1].y) with the SAME I and w:
//   ONE ds_read2_b64 (16B) serves TWO pixels; dual lerp -> v_pk_fma_f32.
// Grid (4,16,16): x-tile 64 (left half), y-tile 32, z = b*4 + chunk(45 ang).
// 1024 blocks = 4/CU (LDS 35.7KB -> 4 resident, 16 waves/CU).
// 15 groups of 3 angles, register prefetch + 1 barrier per group.
// ---------------------------------------------------------------------------
__global__ __launch_bounds__(256, 4) void backproject_kernel(
    const float* __restrict__ xf, float* __restrict__ out) {
  __shared__ __align__(16) v2f P[2][3][RB];   // 35328 B
  __shared__ float2 trig[45];

  const int t     = threadIdx.x;
  const int w     = t >> 6;
  const int lane  = t & 63;
  const int tx    = blockIdx.x;     // 0..3  (left-half x-tiles)
  const int ty    = blockIdx.y;     // 0..15
  const int b     = blockIdx.z >> 2;
  const int chunk = blockIdx.z & 3;
  const int a0    = chunk * 45;

  // zero pad entries of both buffers (both components)
  for (int i = t; i < 2 * 3 * 2 * PAD; i += 256) {
    int bu  = i / 672;
    int rem = i - bu * 672;
    int rr  = rem / 224;
    int o   = rem - rr * 224;
    int j   = (o < PAD) ? o : (o + SS);   // [0,112) U [624,736)
    P[bu][rr][j] = (v2f){0.f, 0.f};
  }
  if (t < 45) {
    float th = (float)(a0 + t) * (float)(M_PI / 180.0);
    float sn, cn;
    sincosf(th, &sn, &cn);
    trig[t] = make_float2(cn * 255.5f, sn * 255.5f);
  }

  const float* src = xf + ((size_t)b * AA + a0) * SS;

  // staging: thread t handles detector pair (2t, 2t+1) of each of 3 rows.
  // fwd float2 + reversed float2 -> one interleaved 16B ds_write_b128 at
  // entry PAD+2t (lane-contiguous 16B stride, 16B aligned).
  float2 fw[3], rv[3];
  auto ld = [&](int g) {
    const float* base = src + (size_t)(g * 3) * SS;
#pragma unroll
    for (int k = 0; k < 3; ++k) {
      const float* row = base + k * SS;
      fw[k] = *(const float2*)(row + 2 * t);
      rv[k] = *(const float2*)(row + 510 - 2 * t);
    }
  };
  auto st = [&](int buf) {
#pragma unroll
    for (int k = 0; k < 3; ++k) {
      // P[PAD+2t] = (data[2t], data[511-2t]); P[PAD+2t+1] = (data[2t+1], data[510-2t])
      float4 q = make_float4(fw[k].x, rv[k].y, fw[k].y, rv[k].x);
      *(float4*)&P[buf][k][PAD + 2 * t] = q;
    }
  };

  const int gx = tx * 64 + lane;    // [0,256)
  // EXACT replication of jnp.linspace(-1,1,512) + f32 mask math (no FMA!)
  const float step = 2.0f / 511.0f;
  const float xg = __fadd_rn(-1.0f, __fmul_rn((float)gx, step));
  float dy[8];  // dy = -yg (negation exact)
#pragma unroll
  for (int kk = 0; kk < 8; ++kk) {
    int gy = ty * 32 + w + 4 * kk;
    dy[kk] = -__fadd_rn(-1.0f, __fmul_rn((float)gy, step));
  }

  const float Kp = 255.5f + (float)PAD;  // = 367.5
  v2f acc[8];
#pragma unroll
  for (int kk = 0; kk < 8; ++kk) acc[kk] = (v2f){0.f, 0.f};

  ld(0);
  st(0);
  __syncthreads();

  int buf = 0;
  for (int g = 0; g < 15; ++g) {
    if (g + 1 < 15) ld(g + 1);
#pragma unroll
    for (int aa = 0; aa < 3; ++aa) {
      const float2 cs = trig[g * 3 + aa];
      const float base = fmaf(xg, cs.x, Kp);
      const v2f* R = P[buf][aa];
#pragma unroll
      for (int kk = 0; kk < 8; ++kk) {
        float p = fmaf(dy[kk], cs.y, base);   // p in (6, 729)
        int   I = (int)p;                     // trunc == floor (p > 0)
#if __has_builtin(__builtin_amdgcn_fractf)
        float wq = __builtin_amdgcn_fractf(p);
#else
        float wq = p - floorf(p);
#endif
        struct { v2f a, b; } q;               // 16B @ 8B-align -> ds_read2_b64
        __builtin_memcpy(&q, R + I, 16);
        v2f d  = q.b - q.a;
        v2f wv = {wq, wq};
        acc[kk] = (acc[kk] + q.a) + wv * d;   // contract -> v_pk_fma_f32
      }
    }
    if (g + 1 < 15) {
      st(buf ^ 1);
      __syncthreads();
      buf ^= 1;
    }
  }

  // epilogue: per-pixel masks (exact f32 replication) + predicated atomics
  const int gxm  = 511 - gx;
  const float xgm = __fadd_rn(-1.0f, __fmul_rn((float)gxm, step));
  const float xx  = __fmul_rn(xg, xg);
  const float xxm = __fmul_rn(xgm, xgm);
#pragma unroll
  for (int kk = 0; kk < 8; ++kk) {
    int gy  = ty * 32 + w + 4 * kk;
    float yg = -dy[kk];
    float s0 = __fadd_rn(xx, __fmul_rn(yg, yg));
    if (s0 <= 1.0f)
      unsafeAtomicAdd(&out[((size_t)b * SS + gy) * SS + gx], acc[kk].x);
    int gym = 511 - gy;
    float ygm = __fadd_rn(-1.0f, __fmul_rn((float)gym, step));
    float s1 = __fadd_rn(xxm, __fmul_rn(ygm, ygm));
    if (s1 <= 1.0f)
      unsafeAtomicAdd(&out[((size_t)b * SS + gym) * SS + gxm], acc[kk].y);
  }
}

}  // namespace

extern "C" void kernel_launch(void* const* d_in, const int* in_sizes, int n_in,
                              void* d_out, int out_size, void* d_ws, size_t ws_size,
                              hipStream_t stream) {
  const float* x   = (const float*)d_in[0];
  float*       out = (float*)d_out;
  float*       xf  = (float*)d_ws;  // [B][A][S] = 1.44 MB

  ramp_zero_kernel<<<dim3(AA / 2, BB), 256, 0, stream>>>(x, xf, out);
  backproject_kernel<<<dim3(4, 16, 16), 256, 0, stream>>>(xf, out);
}